// Round 7
// baseline (564.554 us; speedup 1.0000x reference)
//
#include <hip/hip_runtime.h>
#include <hip/hip_bf16.h>
#include <math.h>

#define N_NODES 100000
#define N_EDGES 1600000
#define D_IN    256
#define D_OUT   128
#define NHEAD   4
#define CH      32
#define GN_EPS  1e-5f

typedef __attribute__((ext_vector_type(8))) short bf16x8;
typedef __attribute__((ext_vector_type(4))) float f32x4;

// ---------- small helpers ----------
__device__ inline float bf2f(unsigned short u) {
    return __uint_as_float(((unsigned int)u) << 16);
}
__device__ inline unsigned short f2bf(float f) {
    unsigned int x = __float_as_uint(f);
    unsigned int r = (x + 0x7fffu + ((x >> 16) & 1u)) >> 16;  // round-nearest-even
    return (unsigned short)r;
}
__device__ inline unsigned int pk2bf(float a, float b) {
    __hip_bfloat162 h = __float22bfloat162_rn(float2{a, b});
    return *(unsigned int*)&h;
}
__device__ inline float mishf(float x) {
    if (x > 15.0f) return x;
    float ex = __expf(x);
    float t = ex * (ex + 2.0f);
    return x * t / (t + 2.0f);
}

// ---------- kernel 0: build Wt (bf16, [512 cols][256 k]) + concat bias ----------
__global__ void prep_w(const float* __restrict__ Wq, const float* __restrict__ Wk,
                       const float* __restrict__ Wv, const float* __restrict__ Wsk,
                       const float* __restrict__ bq, const float* __restrict__ bk,
                       const float* __restrict__ bv, const float* __restrict__ bsk,
                       unsigned short* __restrict__ Wt, float* __restrict__ bcat) {
    int idx = blockIdx.x * 256 + threadIdx.x;   // 512 blocks * 256 = 131072
    int k = idx >> 9;
    int which = (idx >> 7) & 3;
    int c = idx & 127;
    const float* W = (which == 0) ? Wq : (which == 1) ? Wk : (which == 2) ? Wv : Wsk;
    int col = which * 128 + c;
    Wt[(size_t)col * 256 + k] = f2bf(W[(size_t)k * 128 + c]);
    if (idx < 512) {
        const float* b = (which == 0) ? bq : (which == 1) ? bk : (which == 2) ? bv : bsk;
        bcat[idx] = b[c];
    }
}

// ---------- kernel 1: fused 4x GEMM via bf16 MFMA, T14 pipelined staging -------
// grid 1563, block 512 (8 waves). Block tile 64 rows x 512 cols, BK=64, 4 k-steps.
// Wave (wr,wc)=(w>>2,w&3) -> 32x128 of matrix wc, acc[2][8]=64 regs.
// T14: next k-step's A (f32, converted) and B staged to REGISTERS before compute
// of current step, ds_write after barrier -> L2 latency hides under MFMA.
// Epilogue: q/k/v routed through LDS (reuse bs_) -> full 256B-row coalesced HBM
// writes (fixes 32B-segment RMW amplification); skip (f32) written direct (full lines).
__global__ __launch_bounds__(512, 4) void gemm_mfma(
    const float* __restrict__ x, const unsigned short* __restrict__ Wt,
    const float* __restrict__ bcat,
    unsigned short* __restrict__ qb, unsigned short* __restrict__ kb,
    unsigned short* __restrict__ vb, float* __restrict__ skip)
{
    __shared__ unsigned short as_[64 * 64];     // 8 KiB  (64 rows x 64 k)
    __shared__ unsigned short bs_[512 * 64];    // 64 KiB (512 cols x 64 k)
    const int tid = threadIdx.x;
    const int nb = blockIdx.x * 64;

    const int wave = tid >> 6, lane = tid & 63;
    const int lm = lane & 15, lk = lane >> 4;
    const int wr = wave >> 2, wc = wave & 3;    // wr: row half, wc: matrix

    // staging registers (T14 issue-early / write-late)
    float4 av0, av1;
    uint4 breg[8];
    const int srow = tid >> 3, sc = tid & 7;    // A-stage coords (1 chunk/thread)

    auto stage_load = [&](int ks) {
        av0 = make_float4(0.f, 0.f, 0.f, 0.f); av1 = av0;
        int grow = nb + srow;
        if (grow < N_NODES) {
            const float* xp = x + (size_t)grow * D_IN + ks * 64 + sc * 8;
            av0 = *(const float4*)xp;
            av1 = *(const float4*)(xp + 4);
        }
        #pragma unroll
        for (int it = 0; it < 8; ++it) {
            int g = it * 512 + tid;             // 0..4095
            int col = g >> 3, cc = g & 7;
            breg[it] = *(const uint4*)(Wt + (size_t)col * 256 + ks * 64 + cc * 8);
        }
    };
    auto stage_write = [&]() {
        uint4 w;
        w.x = pk2bf(av0.x, av0.y); w.y = pk2bf(av0.z, av0.w);
        w.z = pk2bf(av1.x, av1.y); w.w = pk2bf(av1.z, av1.w);
        *(uint4*)(as_ + srow * 64 + (sc ^ (srow & 7)) * 8) = w;
        #pragma unroll
        for (int it = 0; it < 8; ++it) {
            int g = it * 512 + tid;
            int col = g >> 3, cc = g & 7;
            *(uint4*)(bs_ + col * 64 + (cc ^ (col & 7)) * 8) = breg[it];
        }
    };

    f32x4 acc[2][8] = {};

    stage_load(0);
    stage_write();
    __syncthreads();

    for (int ks = 0; ks < 4; ++ks) {
        if (ks < 3) stage_load(ks + 1);         // issue early: hides under compute

        #pragma unroll
        for (int inner = 0; inner < 2; ++inner) {
            const int ch = inner * 4 + lk;
            bf16x8 a[2], b[8];
            #pragma unroll
            for (int rf = 0; rf < 2; ++rf) {
                int row = wr * 32 + rf * 16 + lm;
                a[rf] = *(const bf16x8*)(as_ + row * 64 + (ch ^ (row & 7)) * 8);
            }
            #pragma unroll
            for (int cf = 0; cf < 8; ++cf) {
                int bcol = wc * 128 + cf * 16 + lm;
                b[cf] = *(const bf16x8*)(bs_ + bcol * 64 + (ch ^ (bcol & 7)) * 8);
            }
            #pragma unroll
            for (int cf = 0; cf < 8; ++cf) {
                acc[0][cf] = __builtin_amdgcn_mfma_f32_16x16x32_bf16(a[0], b[cf], acc[0][cf], 0, 0, 0);
                acc[1][cf] = __builtin_amdgcn_mfma_f32_16x16x32_bf16(a[1], b[cf], acc[1][cf], 0, 0, 0);
            }
        }
        __syncthreads();                        // all waves done reading LDS
        if (ks < 3) {
            stage_write();                      // write late
            __syncthreads();
        }
    }

    // ---- epilogue (C/D layout: col=lane&15, row=(lane>>4)*4+j) ----
    const float* biasp = bcat + wc * 128;
    if (wc < 3) {
        // q/k/v: stage bf16 output tile into LDS (reuse bs_): [wc][64 rows][128 cols]
        #pragma unroll
        for (int rf = 0; rf < 2; ++rf) {
            #pragma unroll
            for (int cf = 0; cf < 8; ++cf) {
                const int col = cf * 16 + lm;
                const float bias = biasp[col];
                #pragma unroll
                for (int j = 0; j < 4; ++j) {
                    const int row = wr * 32 + rf * 16 + lk * 4 + j;
                    bs_[wc * 8192 + row * 128 + col] = f2bf(acc[rf][cf][j] + bias);
                }
            }
        }
    } else {
        // skip (f32): direct stores, 64B full lines per instruction
        #pragma unroll
        for (int rf = 0; rf < 2; ++rf) {
            #pragma unroll
            for (int j = 0; j < 4; ++j) {
                const int r = nb + wr * 32 + rf * 16 + lk * 4 + j;
                if (r < N_NODES) {
                    #pragma unroll
                    for (int cf = 0; cf < 8; ++cf) {
                        const int col = cf * 16 + lm;
                        skip[(size_t)r * D_OUT + col] = acc[rf][cf][j] + biasp[col];
                    }
                }
            }
        }
    }
    __syncthreads();

    // cooperative coalesced write of q/k/v: 3 * 64 rows * 8 chunks = 3072 uint4
    #pragma unroll
    for (int i = 0; i < 6; ++i) {
        int ci = i * 512 + tid;                 // 0..3071
        int m = ci >> 10;                       // matrix 0..2
        int ci2 = ci & 1023;
        int row = ci2 >> 4, ch = ci2 & 15;      // 16 chunks of 8 shorts per row
        int r = nb + row;
        if (r < N_NODES) {
            uint4 v = *(const uint4*)(bs_ + m * 8192 + row * 128 + ch * 8);
            unsigned short* dst = (m == 0) ? qb : (m == 1) ? kb : vb;
            *(uint4*)(dst + (size_t)r * D_OUT + ch * 8) = v;
        }
    }
}

// ---------- kernel 2: degree histogram ----------
__global__ void hist_kernel(const int* __restrict__ dst, int* __restrict__ deg) {
    int e = blockIdx.x * 256 + threadIdx.x;
    if (e < N_EDGES) atomicAdd(&deg[dst[e]], 1);
}

// ---------- kernels 3-5: exclusive scan of deg -> off (2-level) ----------
__global__ __launch_bounds__(256) void scan1(const int* __restrict__ deg,
                                             int* __restrict__ off,
                                             int* __restrict__ bsum) {
    __shared__ int lds[256];
    int t = threadIdx.x;
    int base = blockIdx.x * 1024 + t * 4;
    int d0 = 0, d1 = 0, d2 = 0, d3 = 0;
    if (base + 3 < N_NODES) {
        int4 dd = *(const int4*)(deg + base);
        d0 = dd.x; d1 = dd.y; d2 = dd.z; d3 = dd.w;
    } else {
        if (base     < N_NODES) d0 = deg[base];
        if (base + 1 < N_NODES) d1 = deg[base + 1];
        if (base + 2 < N_NODES) d2 = deg[base + 2];
        if (base + 3 < N_NODES) d3 = deg[base + 3];
    }
    int s = d0 + d1 + d2 + d3;
    lds[t] = s;
    __syncthreads();
    for (int d = 1; d < 256; d <<= 1) {
        int u = (t >= d) ? lds[t - d] : 0;
        __syncthreads();
        lds[t] += u;
        __syncthreads();
    }
    int excl = lds[t] - s;
    if (base     < N_NODES) off[base]     = excl;
    if (base + 1 < N_NODES) off[base + 1] = excl + d0;
    if (base + 2 < N_NODES) off[base + 2] = excl + d0 + d1;
    if (base + 3 < N_NODES) off[base + 3] = excl + d0 + d1 + d2;
    if (t == 255) bsum[blockIdx.x] = lds[255];
}

__global__ void scan2(int* __restrict__ bsum) {  // 1 block, 128 threads, 98 values
    __shared__ int lds[128];
    int t = threadIdx.x;
    int v = (t < 98) ? bsum[t] : 0;
    lds[t] = v;
    __syncthreads();
    for (int d = 1; d < 128; d <<= 1) {
        int u = (t >= d) ? lds[t - d] : 0;
        __syncthreads();
        lds[t] += u;
        __syncthreads();
    }
    if (t < 98) bsum[t] = lds[t] - v;  // exclusive
}

__global__ void scan3(int* __restrict__ off, int* __restrict__ cursor,
                      const int* __restrict__ bsum) {
    int add = bsum[blockIdx.x];
    int base = blockIdx.x * 1024 + threadIdx.x * 4;
    #pragma unroll
    for (int j = 0; j < 4; ++j) {
        int idx = base + j;
        if (idx < N_NODES) {
            int vv = off[idx] + add;
            off[idx] = vv;
            cursor[idx] = vv;
        }
    }
}

// ---------- kernel 6: scatter edges into dst-sorted order ----------
__global__ void scatter_kernel(const int* __restrict__ src, const int* __restrict__ dst,
                               int* __restrict__ cursor, int* __restrict__ ssrc) {
    int e = blockIdx.x * 256 + threadIdx.x;
    if (e < N_EDGES) {
        int d = dst[e];
        int p = atomicAdd(&cursor[d], 1);
        ssrc[p] = src[e];
    }
}

// ---------- kernel 7: per-node attention, single-pass online softmax ----------
// block = 256 = 4 waves; one wave per destination node. 8-edge unroll: 16 gathers
// in flight per wave iteration (latency hiding for random K/V row reads).
// lane -> channels c0=2*lane, c0+1 ; head = lane>>4 (16 lanes per head).
__global__ __launch_bounds__(256) void aggregate(
    const unsigned short* __restrict__ qb, const unsigned short* __restrict__ kb,
    const unsigned short* __restrict__ vb,
    const int* __restrict__ off, const int* __restrict__ endp,
    const int* __restrict__ ssrc, float* __restrict__ out)
{
    const int wave = threadIdx.x >> 6;
    const int lane = threadIdx.x & 63;
    const int n = blockIdx.x * 4 + wave;
    const int c0 = lane * 2;
    const float scale = 0.17677669529663687f;  // 1/sqrt(32)

    unsigned int qv = *(const unsigned int*)(qb + (size_t)n * D_OUT + c0);
    float q0 = bf2f((unsigned short)(qv & 0xffffu));
    float q1 = bf2f((unsigned short)(qv >> 16));

    const int s0 = off[n], s1 = endp[n];

    float m = -1e30f, den = 0.f, a0 = 0.f, a1 = 0.f;

    int i = s0;
    for (; i + 8 <= s1; i += 8) {
        int s[8]; unsigned int kw[8], vw[8]; float p[8], w[8];
        #pragma unroll
        for (int u = 0; u < 8; ++u) s[u] = ssrc[i + u];
        #pragma unroll
        for (int u = 0; u < 8; ++u) kw[u] = *(const unsigned int*)(kb + (size_t)s[u] * D_OUT + c0);
        #pragma unroll
        for (int u = 0; u < 8; ++u) vw[u] = *(const unsigned int*)(vb + (size_t)s[u] * D_OUT + c0);
        #pragma unroll
        for (int u = 0; u < 8; ++u)
            p[u] = q0 * bf2f((unsigned short)(kw[u] & 0xffffu)) + q1 * bf2f((unsigned short)(kw[u] >> 16));
        #pragma unroll
        for (int u = 0; u < 8; ++u) {
            p[u] += __shfl_xor(p[u], 1);
            p[u] += __shfl_xor(p[u], 2);
            p[u] += __shfl_xor(p[u], 4);
            p[u] += __shfl_xor(p[u], 8);
            p[u] *= scale;
        }
        float pm = fmaxf(fmaxf(fmaxf(p[0], p[1]), fmaxf(p[2], p[3])),
                         fmaxf(fmaxf(p[4], p[5]), fmaxf(p[6], p[7])));
        float newm = fmaxf(m, pm);
        float corr = __expf(m - newm);
        float dsum = 0.f, s0a = 0.f, s1a = 0.f;
        #pragma unroll
        for (int u = 0; u < 8; ++u) {
            w[u] = __expf(p[u] - newm);
            dsum += w[u];
            s0a += w[u] * bf2f((unsigned short)(vw[u] & 0xffffu));
            s1a += w[u] * bf2f((unsigned short)(vw[u] >> 16));
        }
        den = den * corr + dsum;
        a0  = a0 * corr + s0a;
        a1  = a1 * corr + s1a;
        m = newm;
    }
    for (; i + 4 <= s1; i += 4) {
        int s[4]; unsigned int kw[4], vw[4]; float p[4], w[4];
        #pragma unroll
        for (int u = 0; u < 4; ++u) s[u] = ssrc[i + u];
        #pragma unroll
        for (int u = 0; u < 4; ++u) kw[u] = *(const unsigned int*)(kb + (size_t)s[u] * D_OUT + c0);
        #pragma unroll
        for (int u = 0; u < 4; ++u) vw[u] = *(const unsigned int*)(vb + (size_t)s[u] * D_OUT + c0);
        #pragma unroll
        for (int u = 0; u < 4; ++u)
            p[u] = q0 * bf2f((unsigned short)(kw[u] & 0xffffu)) + q1 * bf2f((unsigned short)(kw[u] >> 16));
        #pragma unroll
        for (int u = 0; u < 4; ++u) {
            p[u] += __shfl_xor(p[u], 1);
            p[u] += __shfl_xor(p[u], 2);
            p[u] += __shfl_xor(p[u], 4);
            p[u] += __shfl_xor(p[u], 8);
            p[u] *= scale;
        }
        float pm = fmaxf(fmaxf(p[0], p[1]), fmaxf(p[2], p[3]));
        float newm = fmaxf(m, pm);
        float corr = __expf(m - newm);
        float dsum = 0.f, s0a = 0.f, s1a = 0.f;
        #pragma unroll
        for (int u = 0; u < 4; ++u) {
            w[u] = __expf(p[u] - newm);
            dsum += w[u];
            s0a += w[u] * bf2f((unsigned short)(vw[u] & 0xffffu));
            s1a += w[u] * bf2f((unsigned short)(vw[u] >> 16));
        }
        den = den * corr + dsum;
        a0  = a0 * corr + s0a;
        a1  = a1 * corr + s1a;
        m = newm;
    }
    for (; i < s1; ++i) {
        int s = ssrc[i];
        unsigned int kv = *(const unsigned int*)(kb + (size_t)s * D_OUT + c0);
        unsigned int vv = *(const unsigned int*)(vb + (size_t)s * D_OUT + c0);
        float p = q0 * bf2f((unsigned short)(kv & 0xffffu)) + q1 * bf2f((unsigned short)(kv >> 16));
        p += __shfl_xor(p, 1);
        p += __shfl_xor(p, 2);
        p += __shfl_xor(p, 4);
        p += __shfl_xor(p, 8);
        p *= scale;
        float newm = fmaxf(m, p);
        float corr = __expf(m - newm);
        float w = __expf(p - newm);
        den = den * corr + w;
        a0 = a0 * corr + w * bf2f((unsigned short)(vv & 0xffffu));
        a1 = a1 * corr + w * bf2f((unsigned short)(vv >> 16));
        m = newm;
    }

    float invd = (den > 0.f) ? 1.0f / den : 0.f;
    size_t o = (size_t)n * D_OUT + c0;
    float2 sk = *(float2*)(out + o);
    sk.x += a0 * invd;
    sk.y += a1 * invd;
    *(float2*)(out + o) = sk;
}

// ---------- kernel 8: per-channel sum / sumsq ----------
__global__ __launch_bounds__(256) void norm_reduce(const float* __restrict__ out,
                                                   float* __restrict__ sums) {
    const int total = N_NODES * D_OUT;
    const int stride = gridDim.x * 256;           // multiple of 128
    int t = threadIdx.x;
    float s = 0.f, s2 = 0.f;
    for (int i = blockIdx.x * 256 + t; i < total; i += stride) {
        float v = out[i];
        s += v; s2 += v * v;
    }
    __shared__ float ls[256], lq[256];
    ls[t] = s; lq[t] = s2;
    __syncthreads();
    if (t < 128) {
        s  = ls[t] + ls[t + 128];
        s2 = lq[t] + lq[t + 128];
        atomicAdd(&sums[t], s);
        atomicAdd(&sums[128 + t], s2);
    }
}

// ---------- kernel 9: finalize affine coefficients ----------
__global__ void finalize(const float* __restrict__ sums, const float* __restrict__ gw,
                         const float* __restrict__ gb, const float* __restrict__ gms,
                         float* __restrict__ AB) {
    int c = threadIdx.x;  // 128 threads
    const float invN = 1.0f / (float)N_NODES;
    float mean = sums[c] * invN;
    float ex2  = sums[128 + c] * invN;
    float mu = mean * gms[c];
    float var = ex2 - 2.f * mu * mean + mu * mu;
    float inv = rsqrtf(var + GN_EPS);
    float A = gw[c] * inv;
    AB[c] = A;
    AB[128 + c] = gb[c] - mu * A;
}

// ---------- kernel 10: affine + mish (in place on d_out) ----------
__global__ __launch_bounds__(256) void mish_kernel(float* __restrict__ out,
                                                   const float* __restrict__ AB) {
    int i = blockIdx.x * 256 + threadIdx.x;       // one float4 each; grid exact
    int c4 = (i << 2) & 127;
    float4 a  = *(const float4*)(AB + c4);
    float4 b  = *(const float4*)(AB + 128 + c4);
    float4 v  = *(float4*)(out + (size_t)i * 4);
    v.x = mishf(a.x * v.x + b.x);
    v.y = mishf(a.y * v.y + b.y);
    v.z = mishf(a.z * v.z + b.z);
    v.w = mishf(a.w * v.w + b.w);
    *(float4*)(out + (size_t)i * 4) = v;
}

// ---------- launch ----------
extern "C" void kernel_launch(void* const* d_in, const int* in_sizes, int n_in,
                              void* d_out, int out_size, void* d_ws, size_t ws_size,
                              hipStream_t stream) {
    (void)in_sizes; (void)n_in; (void)out_size; (void)ws_size;

    const float* x    = (const float*)d_in[0];
    const int*   ei   = (const int*)d_in[1];
    const float* Wq   = (const float*)d_in[2];
    const float* bq   = (const float*)d_in[3];
    const float* Wk   = (const float*)d_in[4];
    const float* bk   = (const float*)d_in[5];
    const float* Wv   = (const float*)d_in[6];
    const float* bv   = (const float*)d_in[7];
    const float* Wsk  = (const float*)d_in[8];
    const float* bsk  = (const float*)d_in[9];
    const float* gw   = (const float*)d_in[10];
    const float* gb   = (const float*)d_in[11];
    const float* gms  = (const float*)d_in[12];
    float* out = (float*)d_out;

    char* ws = (char*)d_ws;
    size_t o = 0;
    auto alloc = [&](size_t bytes) -> char* {
        char* p = ws + o;
        o += (bytes + 255) & ~(size_t)255;
        return p;
    };

    unsigned short* qb = (unsigned short*)alloc((size_t)N_NODES * D_OUT * 2);
    unsigned short* kb = (unsigned short*)alloc((size_t)N_NODES * D_OUT * 2);
    unsigned short* vb = (unsigned short*)alloc((size_t)N_NODES * D_OUT * 2);
    int* ssrc     = (int*)alloc((size_t)N_EDGES * 4);
    int* deg      = (int*)alloc((size_t)N_NODES * 4);
    int* off      = (int*)alloc((size_t)(N_NODES + 1) * 4);
    int* cursor   = (int*)alloc((size_t)N_NODES * 4);
    int* bsum     = (int*)alloc(512);
    float* sums   = (float*)alloc(1024);
    float* AB     = (float*)alloc(1024);
    unsigned short* Wt = (unsigned short*)alloc((size_t)512 * 256 * 2);
    float* bcat   = (float*)alloc(512 * 4);

    const int* srcp = ei;
    const int* dstp = ei + N_EDGES;

    hipMemsetAsync(deg, 0, (size_t)N_NODES * 4, stream);
    hipMemsetAsync(sums, 0, 256 * 4, stream);

    prep_w<<<512, 256, 0, stream>>>(Wq, Wk, Wv, Wsk, bq, bk, bv, bsk, Wt, bcat);
    gemm_mfma<<<(N_NODES + 63) / 64, 512, 0, stream>>>(x, Wt, bcat, qb, kb, vb, out);

    hist_kernel<<<(N_EDGES + 255) / 256, 256, 0, stream>>>(dstp, deg);
    scan1<<<98, 256, 0, stream>>>(deg, off, bsum);
    scan2<<<1, 128, 0, stream>>>(bsum);
    scan3<<<98, 256, 0, stream>>>(off, cursor, bsum);
    scatter_kernel<<<(N_EDGES + 255) / 256, 256, 0, stream>>>(srcp, dstp, cursor, ssrc);

    aggregate<<<N_NODES / 4, 256, 0, stream>>>(qb, kb, vb, off, cursor, ssrc, out);

    norm_reduce<<<512, 256, 0, stream>>>(out, sums);
    finalize<<<1, 128, 0, stream>>>(sums, gw, gb, gms, AB);
    mish_kernel<<<(N_NODES * D_OUT / 4) / 256, 256, 0, stream>>>(out, AB);
}

// Round 8
// 447.425 us; speedup vs baseline: 1.2618x; 1.2618x over previous
//
#include <hip/hip_runtime.h>
#include <hip/hip_bf16.h>
#include <math.h>

#define N_NODES 100000
#define N_EDGES 1600000
#define D_IN    256
#define D_OUT   128
#define NHEAD   4
#define CH      32
#define GN_EPS  1e-5f

typedef __attribute__((ext_vector_type(8))) short bf16x8;
typedef __attribute__((ext_vector_type(4))) float f32x4;

// ---------- small helpers ----------
__device__ inline float bf2f(unsigned short u) {
    return __uint_as_float(((unsigned int)u) << 16);
}
__device__ inline unsigned short f2bf(float f) {
    unsigned int x = __float_as_uint(f);
    unsigned int r = (x + 0x7fffu + ((x >> 16) & 1u)) >> 16;  // round-nearest-even
    return (unsigned short)r;
}
__device__ inline unsigned int pk2bf(float a, float b) {
    __hip_bfloat162 h = __float22bfloat162_rn(float2{a, b});
    return *(unsigned int*)&h;
}
__device__ inline float mishf(float x) {
    if (x > 15.0f) return x;
    float ex = __expf(x);
    float t = ex * (ex + 2.0f);
    return x * t / (t + 2.0f);
}
// async global->LDS, 16B per lane; LDS dest must be wave-uniform base + lane*16
__device__ inline void gload_lds16(const void* g, void* l) {
    __builtin_amdgcn_global_load_lds(
        (const __attribute__((address_space(1))) unsigned int*)g,
        (__attribute__((address_space(3))) unsigned int*)l,
        16, 0, 0);
}

// ---------- kernel 0: build Wt2 (bf16, PRE-SWIZZLED LDS-image tiles) + bias ----
// Layout: 8 tiles (BK=32). Within tile ks: short offset = col*32 + p*8 + j where
// p = cc ^ ((col>>2)&3), element = W[(ks*32+cc*8+j)*128 + (col&127)] of matrix col>>7.
// stageB then copies each 32KB tile LINEARLY via global_load_lds (m173 pattern).
__global__ void prep_w(const float* __restrict__ Wq, const float* __restrict__ Wk,
                       const float* __restrict__ Wv, const float* __restrict__ Wsk,
                       const float* __restrict__ bq, const float* __restrict__ bk,
                       const float* __restrict__ bv, const float* __restrict__ bsk,
                       unsigned short* __restrict__ Wt2, float* __restrict__ bcat) {
    int idx = blockIdx.x * 256 + threadIdx.x;   // 512 blocks * 256 = 131072
    int k   = idx >> 9;                          // 0..255
    int col = idx & 511;
    int which = col >> 7, c = col & 127;
    const float* W = (which == 0) ? Wq : (which == 1) ? Wk : (which == 2) ? Wv : Wsk;
    int ks = k >> 5, cc = (k >> 3) & 3, j = k & 7;
    int p = cc ^ ((col >> 2) & 3);
    Wt2[(size_t)ks * 16384 + col * 32 + p * 8 + j] = f2bf(W[(size_t)k * 128 + c]);
    if (idx < 512) {
        int w2 = idx >> 7, c2 = idx & 127;
        const float* b = (w2 == 0) ? bq : (w2 == 1) ? bk : (w2 == 2) ? bv : bsk;
        bcat[idx] = b[c2];
    }
}

// ---------- kernel 1: fused 4x GEMM via bf16 MFMA, async B staging -------------
// grid 1563, block 512 (8 waves). Block tile 64 rows x 512 cols, BK=32, 8 k-steps,
// double-buffered LDS (72 KB -> 2 blocks/CU). Wave (wr,wc) -> 32x128 of matrix wc.
// Per iter: issue global_load_lds B(ks+1) + float4 A-load (overlap compute of ks),
// then 10 ds_read_b128 + 16 MFMA, ds_write A(ks+1), ONE barrier.
// Swizzle p = chunk ^ ((row|col)>>2 &3) -> 2-way LDS aliasing only (free, m136).
__global__ __launch_bounds__(512, 4) void gemm_mfma(
    const float* __restrict__ x, const unsigned short* __restrict__ Wt2,
    const float* __restrict__ bcat,
    unsigned short* __restrict__ qb, unsigned short* __restrict__ kb,
    unsigned short* __restrict__ vb, float* __restrict__ skip)
{
    __shared__ unsigned short as_[2][64 * 32];   // 2 x 4 KiB
    __shared__ unsigned short bs_[2][512 * 32];  // 2 x 32 KiB
    const int tid = threadIdx.x;
    const int nb = blockIdx.x * 64;

    const int wave = tid >> 6, lane = tid & 63;
    const int lm = lane & 15, lk = lane >> 4;
    const int wr = wave >> 2, wc = wave & 3;     // wr: row half, wc: matrix

    // A staging: thread -> row tid>>3, k-quad (tid&7)*4 within the 32-k tile
    const int srow = tid >> 3;
    const int sk4  = (tid & 7) * 4;
    float4 areg;

    auto loadA = [&](int ks) {
        areg = make_float4(0.f, 0.f, 0.f, 0.f);
        int grow = nb + srow;
        if (grow < N_NODES)
            areg = *(const float4*)(x + (size_t)grow * D_IN + ks * 32 + sk4);
    };
    auto writeA = [&](int pb) {
        int cc = sk4 >> 3;
        int p = cc ^ ((srow >> 2) & 3);
        uint2 w;
        w.x = pk2bf(areg.x, areg.y);
        w.y = pk2bf(areg.z, areg.w);
        *(uint2*)(as_[pb] + srow * 32 + p * 8 + (sk4 & 7)) = w;
    };
    auto stageB = [&](int ks, int pb) {
        const unsigned short* g = Wt2 + (size_t)ks * 16384;
        #pragma unroll
        for (int it = 0; it < 4; ++it) {
            int u = it * 512 + tid;              // 16B unit, lane-linear per wave
            gload_lds16(g + u * 8, bs_[pb] + u * 8);
        }
    };

    f32x4 acc[2][8] = {};

    stageB(0, 0);
    loadA(0);
    writeA(0);
    __syncthreads();                             // drains vmcnt -> B(0) resident

    for (int ks = 0; ks < 8; ++ks) {
        const int pb = ks & 1;
        if (ks < 7) {
            stageB(ks + 1, pb ^ 1);              // async, overlaps compute below
            loadA(ks + 1);
        }

        bf16x8 a[2], b[8];
        #pragma unroll
        for (int rf = 0; rf < 2; ++rf) {
            int row = wr * 32 + rf * 16 + lm;
            int p = lk ^ ((row >> 2) & 3);
            a[rf] = *(const bf16x8*)(as_[pb] + row * 32 + p * 8);
        }
        #pragma unroll
        for (int cf = 0; cf < 8; ++cf) {
            int col = wc * 128 + cf * 16 + lm;
            int p = lk ^ ((col >> 2) & 3);
            b[cf] = *(const bf16x8*)(bs_[pb] + col * 32 + p * 8);
        }
        #pragma unroll
        for (int cf = 0; cf < 8; ++cf) {
            acc[0][cf] = __builtin_amdgcn_mfma_f32_16x16x32_bf16(a[0], b[cf], acc[0][cf], 0, 0, 0);
            acc[1][cf] = __builtin_amdgcn_mfma_f32_16x16x32_bf16(a[1], b[cf], acc[1][cf], 0, 0, 0);
        }

        if (ks < 7) writeA(pb ^ 1);
        __syncthreads();
    }

    // ---- epilogue (r6-style direct stores; C/D: col=lane&15, row=(lane>>4)*4+j) ----
    unsigned short* dstb = (wc == 0) ? qb : (wc == 1) ? kb : vb;
    const float* biasp = bcat + wc * 128;
    #pragma unroll
    for (int rf = 0; rf < 2; ++rf) {
        #pragma unroll
        for (int j = 0; j < 4; ++j) {
            const int r = nb + wr * 32 + rf * 16 + lk * 4 + j;
            if (r < N_NODES) {
                if (wc == 3) {
                    #pragma unroll
                    for (int cf = 0; cf < 8; ++cf) {
                        const int col = cf * 16 + lm;
                        skip[(size_t)r * D_OUT + col] = acc[rf][cf][j] + biasp[col];
                    }
                } else {
                    #pragma unroll
                    for (int cf = 0; cf < 8; ++cf) {
                        const int col = cf * 16 + lm;
                        dstb[(size_t)r * D_OUT + col] = f2bf(acc[rf][cf][j] + biasp[col]);
                    }
                }
            }
        }
    }
}

// ---------- kernel 2: degree histogram ----------
__global__ void hist_kernel(const int* __restrict__ dst, int* __restrict__ deg) {
    int e = blockIdx.x * 256 + threadIdx.x;
    if (e < N_EDGES) atomicAdd(&deg[dst[e]], 1);
}

// ---------- kernels 3-5: exclusive scan of deg -> off (2-level) ----------
__global__ __launch_bounds__(256) void scan1(const int* __restrict__ deg,
                                             int* __restrict__ off,
                                             int* __restrict__ bsum) {
    __shared__ int lds[256];
    int t = threadIdx.x;
    int base = blockIdx.x * 1024 + t * 4;
    int d0 = 0, d1 = 0, d2 = 0, d3 = 0;
    if (base + 3 < N_NODES) {
        int4 dd = *(const int4*)(deg + base);
        d0 = dd.x; d1 = dd.y; d2 = dd.z; d3 = dd.w;
    } else {
        if (base     < N_NODES) d0 = deg[base];
        if (base + 1 < N_NODES) d1 = deg[base + 1];
        if (base + 2 < N_NODES) d2 = deg[base + 2];
        if (base + 3 < N_NODES) d3 = deg[base + 3];
    }
    int s = d0 + d1 + d2 + d3;
    lds[t] = s;
    __syncthreads();
    for (int d = 1; d < 256; d <<= 1) {
        int u = (t >= d) ? lds[t - d] : 0;
        __syncthreads();
        lds[t] += u;
        __syncthreads();
    }
    int excl = lds[t] - s;
    if (base     < N_NODES) off[base]     = excl;
    if (base + 1 < N_NODES) off[base + 1] = excl + d0;
    if (base + 2 < N_NODES) off[base + 2] = excl + d0 + d1;
    if (base + 3 < N_NODES) off[base + 3] = excl + d0 + d1 + d2;
    if (t == 255) bsum[blockIdx.x] = lds[255];
}

__global__ void scan2(int* __restrict__ bsum) {  // 1 block, 128 threads, 98 values
    __shared__ int lds[128];
    int t = threadIdx.x;
    int v = (t < 98) ? bsum[t] : 0;
    lds[t] = v;
    __syncthreads();
    for (int d = 1; d < 128; d <<= 1) {
        int u = (t >= d) ? lds[t - d] : 0;
        __syncthreads();
        lds[t] += u;
        __syncthreads();
    }
    if (t < 98) bsum[t] = lds[t] - v;  // exclusive
}

__global__ void scan3(int* __restrict__ off, int* __restrict__ cursor,
                      const int* __restrict__ bsum) {
    int add = bsum[blockIdx.x];
    int base = blockIdx.x * 1024 + threadIdx.x * 4;
    #pragma unroll
    for (int j = 0; j < 4; ++j) {
        int idx = base + j;
        if (idx < N_NODES) {
            int vv = off[idx] + add;
            off[idx] = vv;
            cursor[idx] = vv;
        }
    }
}

// ---------- kernel 6: scatter edges into dst-sorted order ----------
__global__ void scatter_kernel(const int* __restrict__ src, const int* __restrict__ dst,
                               int* __restrict__ cursor, int* __restrict__ ssrc) {
    int e = blockIdx.x * 256 + threadIdx.x;
    if (e < N_EDGES) {
        int d = dst[e];
        int p = atomicAdd(&cursor[d], 1);
        ssrc[p] = src[e];
    }
}

// ---------- kernel 7: per-node attention, single-pass online softmax ----------
// block = 256 = 4 waves; one wave per destination node. 8-edge unroll: 16 gathers
// in flight per wave iteration (latency hiding for random K/V row reads).
__global__ __launch_bounds__(256) void aggregate(
    const unsigned short* __restrict__ qb, const unsigned short* __restrict__ kb,
    const unsigned short* __restrict__ vb,
    const int* __restrict__ off, const int* __restrict__ endp,
    const int* __restrict__ ssrc, float* __restrict__ out)
{
    const int wave = threadIdx.x >> 6;
    const int lane = threadIdx.x & 63;
    const int n = blockIdx.x * 4 + wave;
    const int c0 = lane * 2;
    const float scale = 0.17677669529663687f;  // 1/sqrt(32)

    unsigned int qv = *(const unsigned int*)(qb + (size_t)n * D_OUT + c0);
    float q0 = bf2f((unsigned short)(qv & 0xffffu));
    float q1 = bf2f((unsigned short)(qv >> 16));

    const int s0 = off[n], s1 = endp[n];

    float m = -1e30f, den = 0.f, a0 = 0.f, a1 = 0.f;

    int i = s0;
    for (; i + 8 <= s1; i += 8) {
        int s[8]; unsigned int kw[8], vw[8]; float p[8], w[8];
        #pragma unroll
        for (int u = 0; u < 8; ++u) s[u] = ssrc[i + u];
        #pragma unroll
        for (int u = 0; u < 8; ++u) kw[u] = *(const unsigned int*)(kb + (size_t)s[u] * D_OUT + c0);
        #pragma unroll
        for (int u = 0; u < 8; ++u) vw[u] = *(const unsigned int*)(vb + (size_t)s[u] * D_OUT + c0);
        #pragma unroll
        for (int u = 0; u < 8; ++u)
            p[u] = q0 * bf2f((unsigned short)(kw[u] & 0xffffu)) + q1 * bf2f((unsigned short)(kw[u] >> 16));
        #pragma unroll
        for (int u = 0; u < 8; ++u) {
            p[u] += __shfl_xor(p[u], 1);
            p[u] += __shfl_xor(p[u], 2);
            p[u] += __shfl_xor(p[u], 4);
            p[u] += __shfl_xor(p[u], 8);
            p[u] *= scale;
        }
        float pm = fmaxf(fmaxf(fmaxf(p[0], p[1]), fmaxf(p[2], p[3])),
                         fmaxf(fmaxf(p[4], p[5]), fmaxf(p[6], p[7])));
        float newm = fmaxf(m, pm);
        float corr = __expf(m - newm);
        float dsum = 0.f, s0a = 0.f, s1a = 0.f;
        #pragma unroll
        for (int u = 0; u < 8; ++u) {
            w[u] = __expf(p[u] - newm);
            dsum += w[u];
            s0a += w[u] * bf2f((unsigned short)(vw[u] & 0xffffu));
            s1a += w[u] * bf2f((unsigned short)(vw[u] >> 16));
        }
        den = den * corr + dsum;
        a0  = a0 * corr + s0a;
        a1  = a1 * corr + s1a;
        m = newm;
    }
    for (; i + 4 <= s1; i += 4) {
        int s[4]; unsigned int kw[4], vw[4]; float p[4], w[4];
        #pragma unroll
        for (int u = 0; u < 4; ++u) s[u] = ssrc[i + u];
        #pragma unroll
        for (int u = 0; u < 4; ++u) kw[u] = *(const unsigned int*)(kb + (size_t)s[u] * D_OUT + c0);
        #pragma unroll
        for (int u = 0; u < 4; ++u) vw[u] = *(const unsigned int*)(vb + (size_t)s[u] * D_OUT + c0);
        #pragma unroll
        for (int u = 0; u < 4; ++u)
            p[u] = q0 * bf2f((unsigned short)(kw[u] & 0xffffu)) + q1 * bf2f((unsigned short)(kw[u] >> 16));
        #pragma unroll
        for (int u = 0; u < 4; ++u) {
            p[u] += __shfl_xor(p[u], 1);
            p[u] += __shfl_xor(p[u], 2);
            p[u] += __shfl_xor(p[u], 4);
            p[u] += __shfl_xor(p[u], 8);
            p[u] *= scale;
        }
        float pm = fmaxf(fmaxf(p[0], p[1]), fmaxf(p[2], p[3]));
        float newm = fmaxf(m, pm);
        float corr = __expf(m - newm);
        float dsum = 0.f, s0a = 0.f, s1a = 0.f;
        #pragma unroll
        for (int u = 0; u < 4; ++u) {
            w[u] = __expf(p[u] - newm);
            dsum += w[u];
            s0a += w[u] * bf2f((unsigned short)(vw[u] & 0xffffu));
            s1a += w[u] * bf2f((unsigned short)(vw[u] >> 16));
        }
        den = den * corr + dsum;
        a0  = a0 * corr + s0a;
        a1  = a1 * corr + s1a;
        m = newm;
    }
    for (; i < s1; ++i) {
        int s = ssrc[i];
        unsigned int kv = *(const unsigned int*)(kb + (size_t)s * D_OUT + c0);
        unsigned int vv = *(const unsigned int*)(vb + (size_t)s * D_OUT + c0);
        float p = q0 * bf2f((unsigned short)(kv & 0xffffu)) + q1 * bf2f((unsigned short)(kv >> 16));
        p += __shfl_xor(p, 1);
        p += __shfl_xor(p, 2);
        p += __shfl_xor(p, 4);
        p += __shfl_xor(p, 8);
        p *= scale;
        float newm = fmaxf(m, p);
        float corr = __expf(m - newm);
        float w = __expf(p - newm);
        den = den * corr + w;
        a0 = a0 * corr + w * bf2f((unsigned short)(vv & 0xffffu));
        a1 = a1 * corr + w * bf2f((unsigned short)(vv >> 16));
        m = newm;
    }

    float invd = (den > 0.f) ? 1.0f / den : 0.f;
    size_t o = (size_t)n * D_OUT + c0;
    float2 sk = *(float2*)(out + o);
    sk.x += a0 * invd;
    sk.y += a1 * invd;
    *(float2*)(out + o) = sk;
}

// ---------- kernel 8: per-channel sum / sumsq ----------
__global__ __launch_bounds__(256) void norm_reduce(const float* __restrict__ out,
                                                   float* __restrict__ sums) {
    const int total = N_NODES * D_OUT;
    const int stride = gridDim.x * 256;           // multiple of 128
    int t = threadIdx.x;
    float s = 0.f, s2 = 0.f;
    for (int i = blockIdx.x * 256 + t; i < total; i += stride) {
        float v = out[i];
        s += v; s2 += v * v;
    }
    __shared__ float ls[256], lq[256];
    ls[t] = s; lq[t] = s2;
    __syncthreads();
    if (t < 128) {
        s  = ls[t] + ls[t + 128];
        s2 = lq[t] + lq[t + 128];
        atomicAdd(&sums[t], s);
        atomicAdd(&sums[128 + t], s2);
    }
}

// ---------- kernel 9: finalize affine coefficients ----------
__global__ void finalize(const float* __restrict__ sums, const float* __restrict__ gw,
                         const float* __restrict__ gb, const float* __restrict__ gms,
                         float* __restrict__ AB) {
    int c = threadIdx.x;  // 128 threads
    const float invN = 1.0f / (float)N_NODES;
    float mean = sums[c] * invN;
    float ex2  = sums[128 + c] * invN;
    float mu = mean * gms[c];
    float var = ex2 - 2.f * mu * mean + mu * mu;
    float inv = rsqrtf(var + GN_EPS);
    float A = gw[c] * inv;
    AB[c] = A;
    AB[128 + c] = gb[c] - mu * A;
}

// ---------- kernel 10: affine + mish (in place on d_out) ----------
__global__ __launch_bounds__(256) void mish_kernel(float* __restrict__ out,
                                                   const float* __restrict__ AB) {
    int i = blockIdx.x * 256 + threadIdx.x;       // one float4 each; grid exact
    int c4 = (i << 2) & 127;
    float4 a  = *(const float4*)(AB + c4);
    float4 b  = *(const float4*)(AB + 128 + c4);
    float4 v  = *(float4*)(out + (size_t)i * 4);
    v.x = mishf(a.x * v.x + b.x);
    v.y = mishf(a.y * v.y + b.y);
    v.z = mishf(a.z * v.z + b.z);
    v.w = mishf(a.w * v.w + b.w);
    *(float4*)(out + (size_t)i * 4) = v;
}

// ---------- launch ----------
extern "C" void kernel_launch(void* const* d_in, const int* in_sizes, int n_in,
                              void* d_out, int out_size, void* d_ws, size_t ws_size,
                              hipStream_t stream) {
    (void)in_sizes; (void)n_in; (void)out_size; (void)ws_size;

    const float* x    = (const float*)d_in[0];
    const int*   ei   = (const int*)d_in[1];
    const float* Wq   = (const float*)d_in[2];
    const float* bq   = (const float*)d_in[3];
    const float* Wk   = (const float*)d_in[4];
    const float* bk   = (const float*)d_in[5];
    const float* Wv   = (const float*)d_in[6];
    const float* bv   = (const float*)d_in[7];
    const float* Wsk  = (const float*)d_in[8];
    const float* bsk  = (const float*)d_in[9];
    const float* gw   = (const float*)d_in[10];
    const float* gb   = (const float*)d_in[11];
    const float* gms  = (const float*)d_in[12];
    float* out = (float*)d_out;

    char* ws = (char*)d_ws;
    size_t o = 0;
    auto alloc = [&](size_t bytes) -> char* {
        char* p = ws + o;
        o += (bytes + 255) & ~(size_t)255;
        return p;
    };

    unsigned short* qb = (unsigned short*)alloc((size_t)N_NODES * D_OUT * 2);
    unsigned short* kb = (unsigned short*)alloc((size_t)N_NODES * D_OUT * 2);
    unsigned short* vb = (unsigned short*)alloc((size_t)N_NODES * D_OUT * 2);
    int* ssrc     = (int*)alloc((size_t)N_EDGES * 4);
    int* deg      = (int*)alloc((size_t)N_NODES * 4);
    int* off      = (int*)alloc((size_t)(N_NODES + 1) * 4);
    int* cursor   = (int*)alloc((size_t)N_NODES * 4);
    int* bsum     = (int*)alloc(512);
    float* sums   = (float*)alloc(1024);
    float* AB     = (float*)alloc(1024);
    unsigned short* Wt2 = (unsigned short*)alloc((size_t)512 * 256 * 2);
    float* bcat   = (float*)alloc(512 * 4);

    const int* srcp = ei;
    const int* dstp = ei + N_EDGES;

    hipMemsetAsync(deg, 0, (size_t)N_NODES * 4, stream);
    hipMemsetAsync(sums, 0, 256 * 4, stream);

    prep_w<<<512, 256, 0, stream>>>(Wq, Wk, Wv, Wsk, bq, bk, bv, bsk, Wt2, bcat);
    gemm_mfma<<<(N_NODES + 63) / 64, 512, 0, stream>>>(x, Wt2, bcat, qb, kb, vb, out);

    hist_kernel<<<(N_EDGES + 255) / 256, 256, 0, stream>>>(dstp, deg);
    scan1<<<98, 256, 0, stream>>>(deg, off, bsum);
    scan2<<<1, 128, 0, stream>>>(bsum);
    scan3<<<98, 256, 0, stream>>>(off, cursor, bsum);
    scatter_kernel<<<(N_EDGES + 255) / 256, 256, 0, stream>>>(srcp, dstp, cursor, ssrc);

    aggregate<<<N_NODES / 4, 256, 0, stream>>>(qb, kb, vb, off, cursor, ssrc, out);

    norm_reduce<<<512, 256, 0, stream>>>(out, sums);
    finalize<<<1, 128, 0, stream>>>(sums, gw, gb, gms, AB);
    mish_kernel<<<(N_NODES * D_OUT / 4) / 256, 256, 0, stream>>>(out, AB);
}

// Round 9
// 364.078 us; speedup vs baseline: 1.5506x; 1.2289x over previous
//
#include <hip/hip_runtime.h>
#include <hip/hip_bf16.h>
#include <math.h>

#define N_NODES 100000
#define N_EDGES 1600000
#define D_IN    256
#define D_OUT   128
#define NHEAD   4
#define CH      32
#define GN_EPS  1e-5f

#define BSHIFT  9
#define BNODES  512
#define NBUCK   196   // ceil(100000/512)

typedef __attribute__((ext_vector_type(8))) short bf16x8;
typedef __attribute__((ext_vector_type(4))) float f32x4;

// ---------- small helpers ----------
__device__ inline float bf2f(unsigned short u) {
    return __uint_as_float(((unsigned int)u) << 16);
}
__device__ inline unsigned short f2bf(float f) {
    unsigned int x = __float_as_uint(f);
    unsigned int r = (x + 0x7fffu + ((x >> 16) & 1u)) >> 16;  // round-nearest-even
    return (unsigned short)r;
}
__device__ inline unsigned int pk2bf(float a, float b) {
    __hip_bfloat162 h = __float22bfloat162_rn(float2{a, b});
    return *(unsigned int*)&h;
}
__device__ inline float mishf(float x) {
    if (x > 15.0f) return x;
    float ex = __expf(x);
    float t = ex * (ex + 2.0f);
    return x * t / (t + 2.0f);
}
// async global->LDS, 16B per lane; LDS dest must be wave-uniform base + lane*16
__device__ inline void gload_lds16(const void* g, void* l) {
    __builtin_amdgcn_global_load_lds(
        (const __attribute__((address_space(1))) unsigned int*)g,
        (__attribute__((address_space(3))) unsigned int*)l,
        16, 0, 0);
}

// ---------- kernel 0: build Wt2 (bf16, PRE-SWIZZLED LDS-image tiles) + bias ----
__global__ void prep_w(const float* __restrict__ Wq, const float* __restrict__ Wk,
                       const float* __restrict__ Wv, const float* __restrict__ Wsk,
                       const float* __restrict__ bq, const float* __restrict__ bk,
                       const float* __restrict__ bv, const float* __restrict__ bsk,
                       unsigned short* __restrict__ Wt2, float* __restrict__ bcat) {
    int idx = blockIdx.x * 256 + threadIdx.x;   // 512 blocks * 256 = 131072
    int k   = idx >> 9;                          // 0..255
    int col = idx & 511;
    int which = col >> 7, c = col & 127;
    const float* W = (which == 0) ? Wq : (which == 1) ? Wk : (which == 2) ? Wv : Wsk;
    int ks = k >> 5, cc = (k >> 3) & 3, j = k & 7;
    int p = cc ^ ((col >> 2) & 3);
    Wt2[(size_t)ks * 16384 + col * 32 + p * 8 + j] = f2bf(W[(size_t)k * 128 + c]);
    if (idx < 512) {
        int w2 = idx >> 7, c2 = idx & 127;
        const float* b = (w2 == 0) ? bq : (w2 == 1) ? bk : (w2 == 2) ? bv : bsk;
        bcat[idx] = b[c2];
    }
}

// ---------- kernel 1: fused 4x GEMM via bf16 MFMA, async B staging (r8 proven) --
__global__ __launch_bounds__(512, 4) void gemm_mfma(
    const float* __restrict__ x, const unsigned short* __restrict__ Wt2,
    const float* __restrict__ bcat,
    unsigned short* __restrict__ qb, unsigned short* __restrict__ kb,
    unsigned short* __restrict__ vb, float* __restrict__ skip)
{
    __shared__ unsigned short as_[2][64 * 32];   // 2 x 4 KiB
    __shared__ unsigned short bs_[2][512 * 32];  // 2 x 32 KiB
    const int tid = threadIdx.x;
    const int nb = blockIdx.x * 64;

    const int wave = tid >> 6, lane = tid & 63;
    const int lm = lane & 15, lk = lane >> 4;
    const int wr = wave >> 2, wc = wave & 3;     // wr: row half, wc: matrix

    const int srow = tid >> 3;
    const int sk4  = (tid & 7) * 4;
    float4 areg;

    auto loadA = [&](int ks) {
        areg = make_float4(0.f, 0.f, 0.f, 0.f);
        int grow = nb + srow;
        if (grow < N_NODES)
            areg = *(const float4*)(x + (size_t)grow * D_IN + ks * 32 + sk4);
    };
    auto writeA = [&](int pb) {
        int cc = sk4 >> 3;
        int p = cc ^ ((srow >> 2) & 3);
        uint2 w;
        w.x = pk2bf(areg.x, areg.y);
        w.y = pk2bf(areg.z, areg.w);
        *(uint2*)(as_[pb] + srow * 32 + p * 8 + (sk4 & 7)) = w;
    };
    auto stageB = [&](int ks, int pb) {
        const unsigned short* g = Wt2 + (size_t)ks * 16384;
        #pragma unroll
        for (int it = 0; it < 4; ++it) {
            int u = it * 512 + tid;              // 16B unit, lane-linear per wave
            gload_lds16(g + u * 8, bs_[pb] + u * 8);
        }
    };

    f32x4 acc[2][8] = {};

    stageB(0, 0);
    loadA(0);
    writeA(0);
    __syncthreads();

    for (int ks = 0; ks < 8; ++ks) {
        const int pb = ks & 1;
        if (ks < 7) {
            stageB(ks + 1, pb ^ 1);
            loadA(ks + 1);
        }

        bf16x8 a[2], b[8];
        #pragma unroll
        for (int rf = 0; rf < 2; ++rf) {
            int row = wr * 32 + rf * 16 + lm;
            int p = lk ^ ((row >> 2) & 3);
            a[rf] = *(const bf16x8*)(as_[pb] + row * 32 + p * 8);
        }
        #pragma unroll
        for (int cf = 0; cf < 8; ++cf) {
            int col = wc * 128 + cf * 16 + lm;
            int p = lk ^ ((col >> 2) & 3);
            b[cf] = *(const bf16x8*)(bs_[pb] + col * 32 + p * 8);
        }
        #pragma unroll
        for (int cf = 0; cf < 8; ++cf) {
            acc[0][cf] = __builtin_amdgcn_mfma_f32_16x16x32_bf16(a[0], b[cf], acc[0][cf], 0, 0, 0);
            acc[1][cf] = __builtin_amdgcn_mfma_f32_16x16x32_bf16(a[1], b[cf], acc[1][cf], 0, 0, 0);
        }

        if (ks < 7) writeA(pb ^ 1);
        __syncthreads();
    }

    unsigned short* dstb = (wc == 0) ? qb : (wc == 1) ? kb : vb;
    const float* biasp = bcat + wc * 128;
    #pragma unroll
    for (int rf = 0; rf < 2; ++rf) {
        #pragma unroll
        for (int j = 0; j < 4; ++j) {
            const int r = nb + wr * 32 + rf * 16 + lk * 4 + j;
            if (r < N_NODES) {
                if (wc == 3) {
                    #pragma unroll
                    for (int cf = 0; cf < 8; ++cf) {
                        const int col = cf * 16 + lm;
                        skip[(size_t)r * D_OUT + col] = acc[rf][cf][j] + biasp[col];
                    }
                } else {
                    #pragma unroll
                    for (int cf = 0; cf < 8; ++cf) {
                        const int col = cf * 16 + lm;
                        dstb[(size_t)r * D_OUT + col] = f2bf(acc[rf][cf][j] + biasp[col]);
                    }
                }
            }
        }
    }
}

// ---------- kernel 2: degree histogram ----------
__global__ void hist_kernel(const int* __restrict__ dst, int* __restrict__ deg) {
    int e = blockIdx.x * 256 + threadIdx.x;
    if (e < N_EDGES) atomicAdd(&deg[dst[e]], 1);
}

// ---------- kernels 3-5: exclusive scan of deg -> off (2-level) ----------
__global__ __launch_bounds__(256) void scan1(const int* __restrict__ deg,
                                             int* __restrict__ off,
                                             int* __restrict__ bsum) {
    __shared__ int lds[256];
    int t = threadIdx.x;
    int base = blockIdx.x * 1024 + t * 4;
    int d0 = 0, d1 = 0, d2 = 0, d3 = 0;
    if (base + 3 < N_NODES) {
        int4 dd = *(const int4*)(deg + base);
        d0 = dd.x; d1 = dd.y; d2 = dd.z; d3 = dd.w;
    } else {
        if (base     < N_NODES) d0 = deg[base];
        if (base + 1 < N_NODES) d1 = deg[base + 1];
        if (base + 2 < N_NODES) d2 = deg[base + 2];
        if (base + 3 < N_NODES) d3 = deg[base + 3];
    }
    int s = d0 + d1 + d2 + d3;
    lds[t] = s;
    __syncthreads();
    for (int d = 1; d < 256; d <<= 1) {
        int u = (t >= d) ? lds[t - d] : 0;
        __syncthreads();
        lds[t] += u;
        __syncthreads();
    }
    int excl = lds[t] - s;
    if (base     < N_NODES) off[base]     = excl;
    if (base + 1 < N_NODES) off[base + 1] = excl + d0;
    if (base + 2 < N_NODES) off[base + 2] = excl + d0 + d1;
    if (base + 3 < N_NODES) off[base + 3] = excl + d0 + d1 + d2;
    if (t == 255) bsum[blockIdx.x] = lds[255];
}

__global__ void scan2(int* __restrict__ bsum) {  // 1 block, 128 threads, 98 values
    __shared__ int lds[128];
    int t = threadIdx.x;
    int v = (t < 98) ? bsum[t] : 0;
    lds[t] = v;
    __syncthreads();
    for (int d = 1; d < 128; d <<= 1) {
        int u = (t >= d) ? lds[t - d] : 0;
        __syncthreads();
        lds[t] += u;
        __syncthreads();
    }
    if (t < 98) bsum[t] = lds[t] - v;  // exclusive
}

__global__ void scan3(int* __restrict__ off, const int* __restrict__ bsum) {
    int add = bsum[blockIdx.x];
    int base = blockIdx.x * 1024 + threadIdx.x * 4;
    #pragma unroll
    for (int j = 0; j < 4; ++j) {
        int idx = base + j;
        if (idx < N_NODES) off[idx] += add;
    }
}

// ---------- kernel 6a: init per-bucket cursors from CSR offsets ----------
__global__ void binit(const int* __restrict__ off, int* __restrict__ bcur) {
    int t = threadIdx.x;
    if (t < NBUCK) bcur[t] = off[t * BNODES];
}

// ---------- kernel 6b: phase-1 bucket scatter (edges -> bucket-contiguous) ----
// Each block: 4096 edges. LDS count per bucket -> one global atomic per bucket
// -> place (src,dst) pairs into the bucket's FINAL CSR REGION of tpair.
__global__ __launch_bounds__(256) void bucket1(const int* __restrict__ src,
                                               const int* __restrict__ dst,
                                               int* __restrict__ bcur,
                                               int2* __restrict__ tpair) {
    __shared__ int cnt[NBUCK], base[NBUCK], cnt2[NBUCK];
    const int t = threadIdx.x;
    const int e0 = blockIdx.x * 4096;
    if (t < NBUCK) { cnt[t] = 0; cnt2[t] = 0; }
    __syncthreads();

    #pragma unroll
    for (int u = 0; u < 16; ++u) {
        int e = e0 + u * 256 + t;
        if (e < N_EDGES) atomicAdd(&cnt[dst[e] >> BSHIFT], 1);
    }
    __syncthreads();
    if (t < NBUCK && cnt[t] > 0) base[t] = atomicAdd(&bcur[t], cnt[t]);
    __syncthreads();

    #pragma unroll
    for (int u = 0; u < 16; ++u) {
        int e = e0 + u * 256 + t;
        if (e < N_EDGES) {
            int d = dst[e];
            int b = d >> BSHIFT;
            int idx = atomicAdd(&cnt2[b], 1);
            tpair[base[b] + idx] = make_int2(src[e], d);
        }
    }
}

// ---------- kernel 6c: phase-2 exact placement within bucket (LDS cursors) ----
// One block per bucket; writes confined to the bucket's ~64KB ssrc region.
__global__ __launch_bounds__(256) void bucket2(const int* __restrict__ off,
                                               const int2* __restrict__ tpair,
                                               int* __restrict__ ssrc) {
    __shared__ int cur[BNODES];
    const int b = blockIdx.x;
    const int t = threadIdx.x;
    const int n0 = b * BNODES;
    #pragma unroll
    for (int u = 0; u < 2; ++u) {
        int idx = n0 + u * 256 + t;
        cur[u * 256 + t] = (idx < N_NODES) ? off[idx] : 0;
    }
    __syncthreads();

    const int start = off[n0];
    const int end = (b == NBUCK - 1) ? N_EDGES : off[n0 + BNODES];
    for (int i = start + t; i < end; i += 256) {
        int2 pr = tpair[i];
        int q = atomicAdd(&cur[pr.y - n0], 1);
        ssrc[q] = pr.x;
    }
}

// ---------- kernel 7: per-node attention, 16-lane-per-edge online softmax -----
// One wave per node; 4 groups of 16 lanes each process a strided edge subset.
// Lane holds 8 channels (cbase=sl*8) of head sl>>2; head-dot = 2 shuffles over
// 4 lanes. Per-group independent (m,den,acc); merged via xor-16/32 at the end.
__global__ __launch_bounds__(256) void aggregate(
    const unsigned short* __restrict__ qb, const unsigned short* __restrict__ kb,
    const unsigned short* __restrict__ vb,
    const int* __restrict__ off, const int* __restrict__ deg,
    const int* __restrict__ ssrc, float* __restrict__ out)
{
    const int wave = threadIdx.x >> 6;
    const int lane = threadIdx.x & 63;
    const int n = blockIdx.x * 4 + wave;
    const int grp = lane >> 4, sl = lane & 15;
    const int cbase = sl * 8;
    const float scale = 0.17677669529663687f;  // 1/sqrt(32)

    bf16x8 q8 = *(const bf16x8*)(qb + (size_t)n * D_OUT + cbase);
    float qf[8];
    #pragma unroll
    for (int j = 0; j < 8; ++j) qf[j] = bf2f((unsigned short)q8[j]);

    const int s0 = off[n];
    const int s1 = s0 + deg[n];

    float m = -1e30f, den = 0.f;
    float acc[8] = {0.f, 0.f, 0.f, 0.f, 0.f, 0.f, 0.f, 0.f};

    auto edge = [&](int i) {
        int s = ssrc[i];
        bf16x8 k8 = *(const bf16x8*)(kb + (size_t)s * D_OUT + cbase);
        bf16x8 v8 = *(const bf16x8*)(vb + (size_t)s * D_OUT + cbase);
        float part = 0.f;
        #pragma unroll
        for (int j = 0; j < 8; ++j) part += qf[j] * bf2f((unsigned short)k8[j]);
        part += __shfl_xor(part, 1);
        part += __shfl_xor(part, 2);
        float p = part * scale;
        float newm = fmaxf(m, p);
        float corr = __expf(m - newm);
        float w = __expf(p - newm);
        den = den * corr + w;
        #pragma unroll
        for (int j = 0; j < 8; ++j)
            acc[j] = acc[j] * corr + w * bf2f((unsigned short)v8[j]);
        m = newm;
    };

    int i = s0 + grp;
    for (; i + 4 < s1; i += 8) { edge(i); edge(i + 4); }
    if (i < s1) edge(i);

    // merge the 4 groups (lanes sl, sl+16, sl+32, sl+48 hold same channels)
    #pragma unroll
    for (int d = 16; d <= 32; d <<= 1) {
        float mo = __shfl_xor(m, d);
        float deno = __shfl_xor(den, d);
        float M = fmaxf(m, mo);
        float c1 = __expf(m - M), c2 = __expf(mo - M);
        den = den * c1 + deno * c2;
        #pragma unroll
        for (int j = 0; j < 8; ++j) {
            float ao = __shfl_xor(acc[j], d);
            acc[j] = acc[j] * c1 + ao * c2;
        }
        m = M;
    }

    if (grp == 0) {
        float invd = (den > 0.f) ? 1.0f / den : 0.f;
        size_t o = (size_t)n * D_OUT + cbase;
        float4 o0 = *(float4*)(out + o);
        float4 o1 = *(float4*)(out + o + 4);
        o0.x += acc[0] * invd; o0.y += acc[1] * invd;
        o0.z += acc[2] * invd; o0.w += acc[3] * invd;
        o1.x += acc[4] * invd; o1.y += acc[5] * invd;
        o1.z += acc[6] * invd; o1.w += acc[7] * invd;
        *(float4*)(out + o) = o0;
        *(float4*)(out + o + 4) = o1;
    }
}

// ---------- kernel 8: per-channel sum / sumsq ----------
__global__ __launch_bounds__(256) void norm_reduce(const float* __restrict__ out,
                                                   float* __restrict__ sums) {
    const int total = N_NODES * D_OUT;
    const int stride = gridDim.x * 256;           // multiple of 128
    int t = threadIdx.x;
    float s = 0.f, s2 = 0.f;
    for (int i = blockIdx.x * 256 + t; i < total; i += stride) {
        float v = out[i];
        s += v; s2 += v * v;
    }
    __shared__ float ls[256], lq[256];
    ls[t] = s; lq[t] = s2;
    __syncthreads();
    if (t < 128) {
        s  = ls[t] + ls[t + 128];
        s2 = lq[t] + lq[t + 128];
        atomicAdd(&sums[t], s);
        atomicAdd(&sums[128 + t], s2);
    }
}

// ---------- kernel 9: finalize affine coefficients ----------
__global__ void finalize(const float* __restrict__ sums, const float* __restrict__ gw,
                         const float* __restrict__ gb, const float* __restrict__ gms,
                         float* __restrict__ AB) {
    int c = threadIdx.x;  // 128 threads
    const float invN = 1.0f / (float)N_NODES;
    float mean = sums[c] * invN;
    float ex2  = sums[128 + c] * invN;
    float mu = mean * gms[c];
    float var = ex2 - 2.f * mu * mean + mu * mu;
    float inv = rsqrtf(var + GN_EPS);
    float A = gw[c] * inv;
    AB[c] = A;
    AB[128 + c] = gb[c] - mu * A;
}

// ---------- kernel 10: affine + mish (in place on d_out) ----------
__global__ __launch_bounds__(256) void mish_kernel(float* __restrict__ out,
                                                   const float* __restrict__ AB) {
    int i = blockIdx.x * 256 + threadIdx.x;       // one float4 each; grid exact
    int c4 = (i << 2) & 127;
    float4 a  = *(const float4*)(AB + c4);
    float4 b  = *(const float4*)(AB + 128 + c4);
    float4 v  = *(float4*)(out + (size_t)i * 4);
    v.x = mishf(a.x * v.x + b.x);
    v.y = mishf(a.y * v.y + b.y);
    v.z = mishf(a.z * v.z + b.z);
    v.w = mishf(a.w * v.w + b.w);
    *(float4*)(out + (size_t)i * 4) = v;
}

// ---------- launch ----------
extern "C" void kernel_launch(void* const* d_in, const int* in_sizes, int n_in,
                              void* d_out, int out_size, void* d_ws, size_t ws_size,
                              hipStream_t stream) {
    (void)in_sizes; (void)n_in; (void)out_size; (void)ws_size;

    const float* x    = (const float*)d_in[0];
    const int*   ei   = (const int*)d_in[1];
    const float* Wq   = (const float*)d_in[2];
    const float* bq   = (const float*)d_in[3];
    const float* Wk   = (const float*)d_in[4];
    const float* bk   = (const float*)d_in[5];
    const float* Wv   = (const float*)d_in[6];
    const float* bv   = (const float*)d_in[7];
    const float* Wsk  = (const float*)d_in[8];
    const float* bsk  = (const float*)d_in[9];
    const float* gw   = (const float*)d_in[10];
    const float* gb   = (const float*)d_in[11];
    const float* gms  = (const float*)d_in[12];
    float* out = (float*)d_out;

    char* ws = (char*)d_ws;
    size_t o = 0;
    auto alloc = [&](size_t bytes) -> char* {
        char* p = ws + o;
        o += (bytes + 255) & ~(size_t)255;
        return p;
    };

    unsigned short* qb = (unsigned short*)alloc((size_t)N_NODES * D_OUT * 2);
    unsigned short* kb = (unsigned short*)alloc((size_t)N_NODES * D_OUT * 2);
    unsigned short* vb = (unsigned short*)alloc((size_t)N_NODES * D_OUT * 2);
    int* ssrc     = (int*)alloc((size_t)N_EDGES * 4);
    int2* tpair   = (int2*)alloc((size_t)N_EDGES * 8);
    int* deg      = (int*)alloc((size_t)N_NODES * 4);
    int* off      = (int*)alloc((size_t)(N_NODES + 1) * 4);
    int* bcur     = (int*)alloc(1024);
    int* bsum     = (int*)alloc(512);
    float* sums   = (float*)alloc(1024);
    float* AB     = (float*)alloc(1024);
    unsigned short* Wt2 = (unsigned short*)alloc((size_t)512 * 256 * 2);
    float* bcat   = (float*)alloc(512 * 4);

    const int* srcp = ei;
    const int* dstp = ei + N_EDGES;

    hipMemsetAsync(deg, 0, (size_t)N_NODES * 4, stream);
    hipMemsetAsync(sums, 0, 256 * 4, stream);

    prep_w<<<512, 256, 0, stream>>>(Wq, Wk, Wv, Wsk, bq, bk, bv, bsk, Wt2, bcat);
    gemm_mfma<<<(N_NODES + 63) / 64, 512, 0, stream>>>(x, Wt2, bcat, qb, kb, vb, out);

    hist_kernel<<<(N_EDGES + 255) / 256, 256, 0, stream>>>(dstp, deg);
    scan1<<<98, 256, 0, stream>>>(deg, off, bsum);
    scan2<<<1, 128, 0, stream>>>(bsum);
    scan3<<<98, 256, 0, stream>>>(off, bsum);

    binit<<<1, 256, 0, stream>>>(off, bcur);
    bucket1<<<(N_EDGES + 4095) / 4096, 256, 0, stream>>>(srcp, dstp, bcur, tpair);
    bucket2<<<NBUCK, 256, 0, stream>>>(off, tpair, ssrc);

    aggregate<<<N_NODES / 4, 256, 0, stream>>>(qb, kb, vb, off, deg, ssrc, out);

    norm_reduce<<<512, 256, 0, stream>>>(out, sums);
    finalize<<<1, 128, 0, stream>>>(sums, gw, gb, gms, AB);
    mish_kernel<<<(N_NODES * D_OUT / 4) / 256, 256, 0, stream>>>(out, AB);
}